// Round 10
// baseline (490.227 us; speedup 1.0000x reference)
//
#include <hip/hip_runtime.h>
#include <hip/hip_bf16.h>
#include <math.h>

#define NB 4
#define S_TOK 12544
#define N_TOTAL 25690112ull
#define EPS 1e-5f

typedef short s16x8 __attribute__((ext_vector_type(8)));
typedef short s16x4 __attribute__((ext_vector_type(4)));
typedef float f32x4 __attribute__((ext_vector_type(4)));

__device__ __forceinline__ short f2bf(float f) {
    unsigned u = __builtin_bit_cast(unsigned, f);
    u += 0x7fffu + ((u >> 16) & 1u);
    return (short)(u >> 16);
}
__device__ __forceinline__ float bf2f(short s) {
    return __builtin_bit_cast(float, ((unsigned)(unsigned short)s) << 16);
}

// ---------------------------------------------------------------------------
// Weights -> bf16. wb: [0,32768) pw1 | [32768,49152) k | [49152,65536) q |
// [65536,196608) rp.  Also builds stacked K/Q bias (512 floats).
// ---------------------------------------------------------------------------
__global__ __launch_bounds__(256) void prep_k(
    const float* __restrict__ pw1_w, const float* __restrict__ k_w,
    const float* __restrict__ q_w, const float* __restrict__ rp_w,
    const float* __restrict__ k_b, const float* __restrict__ q_b,
    short* __restrict__ wb, float* __restrict__ biaskq)
{
    int g = blockIdx.x * 256 + threadIdx.x;
    if (g < 512) biaskq[g] = g < 256 ? k_b[g] : q_b[g - 256];
    int i = g;
#pragma unroll
    for (int r = 0; r < 4; ++r, i += 49152) {
        float v;
        if (i < 32768) v = pw1_w[i];
        else if (i < 49152) v = k_w[i - 32768];
        else if (i < 65536) v = q_w[i - 49152];
        else v = rp_w[i - 65536];
        wb[i] = f2bf(v);
    }
}

// ---------------------------------------------------------------------------
// MFMA GEMM (XTRANS path): O[m][s] = sum_k W[m][k]*X[k][s] + bias[m]
//  X fp32 [K][S] transpose+convert staged (u32-packed LDS writes).
//  OUTBF16: bf16 out.  KSPLIT: k-chunks -> separate partial buffers.
//  16B LDS blocks XOR-swizzled by (row&7), same involution on both sides.
// ---------------------------------------------------------------------------
template<int NT, int WM, int WS, bool OUTBF16, int KSPLIT>
__global__ __launch_bounds__(NT) void gemm_mfma(
    const short* __restrict__ Wb, const float* __restrict__ bias,
    const float* __restrict__ Xv, void* __restrict__ Ov,
    int M, int K, int S)
{
    constexpr int BM = WM * 64;
    constexpr int BS = WS * 64;
    __shared__ __align__(16) short Xt[BS][64];
    __shared__ __align__(16) short Wt[BM][64];

    const int tid  = threadIdx.x;
    const int lane = tid & 63;
    const int wave = tid >> 6;
    const int kc   = (KSPLIT > 1) ? (int)(blockIdx.x % KSPLIT) : 0;
    const int mb   = ((KSPLIT > 1) ? (int)(blockIdx.x / KSPLIT) : (int)blockIdx.x) * BM;
    const int sb   = blockIdx.y * BS;
    const size_t nb = blockIdx.z;

    const int wm0 = (wave / WS) * 64;
    const int ws0 = (wave % WS) * 64;

    f32x4 acc[4][4];
#pragma unroll
    for (int i = 0; i < 4; ++i)
#pragma unroll
        for (int j = 0; j < 4; ++j) acc[i][j] = (f32x4){0.f, 0.f, 0.f, 0.f};

    const int kLen = K / KSPLIT;
    const int kBeg = kc * kLen;
    const int srow = tid >> 1;        // W staging row
    const int sb4  = (tid & 1) * 4;

    for (int k0 = kBeg; k0 < kBeg + kLen; k0 += 64) {
        __syncthreads();
        {   // W stage: NT/2 rows, 2 threads/row
            const short* wrow = Wb + (size_t)(mb + srow) * K + k0;
            const int sw = srow & 7;
#pragma unroll
            for (int b = 0; b < 4; ++b) {
                const int blk = sb4 + b;
                s16x8 v = *(const s16x8*)(wrow + ((blk ^ sw) * 8));
                *(s16x8*)(&Wt[srow][blk * 8]) = v;
            }
        }
        {   // X fp32 [K][S] -> transpose+convert, u32-packed (2 k per write)
            const int kr2 = tid & 31;               // k-pair: k = 2*kr2, 2*kr2+1
            constexpr int SPAN2 = (BS * 32) / NT;   // u32 writes (s-span) per thread
            const int s0 = (tid >> 5) * SPAN2;
            const float* xr0 = Xv + nb * (size_t)K * S
                               + (size_t)(k0 + 2 * kr2) * S + sb + s0;
            const float* xr1 = xr0 + S;
            const int blk = kr2 >> 2;               // 16B block within row
            const int sub = (kr2 * 4) & 15;         // byte offset within block
            char* base = (char*)Xt;
#pragma unroll
            for (int u = 0; u < SPAN2 / 4; ++u) {
                float4 a  = *(const float4*)(xr0 + u * 4);
                float4 b4 = *(const float4*)(xr1 + u * 4);
                const int s_ = s0 + u * 4;
                unsigned p0 = (unsigned)(unsigned short)f2bf(a.x) | ((unsigned)(unsigned short)f2bf(b4.x) << 16);
                unsigned p1 = (unsigned)(unsigned short)f2bf(a.y) | ((unsigned)(unsigned short)f2bf(b4.y) << 16);
                unsigned p2 = (unsigned)(unsigned short)f2bf(a.z) | ((unsigned)(unsigned short)f2bf(b4.z) << 16);
                unsigned p3 = (unsigned)(unsigned short)f2bf(a.w) | ((unsigned)(unsigned short)f2bf(b4.w) << 16);
                *(unsigned*)(base + (s_ + 0) * 128 + ((blk ^ ((s_ + 0) & 7)) << 4) + sub) = p0;
                *(unsigned*)(base + (s_ + 1) * 128 + ((blk ^ ((s_ + 1) & 7)) << 4) + sub) = p1;
                *(unsigned*)(base + (s_ + 2) * 128 + ((blk ^ ((s_ + 2) & 7)) << 4) + sub) = p2;
                *(unsigned*)(base + (s_ + 3) * 128 + ((blk ^ ((s_ + 3) & 7)) << 4) + sub) = p3;
            }
        }
        __syncthreads();

#pragma unroll
        for (int kk = 0; kk < 2; ++kk) {
            s16x8 af[4], bg[4];
#pragma unroll
            for (int i = 0; i < 4; ++i) {
                const int row = ws0 + i * 16 + (lane & 15);
                const int blk = (kk * 4 + (lane >> 4)) ^ (row & 7);
                af[i] = *(const s16x8*)((const char*)Xt + row * 128 + blk * 16);
            }
#pragma unroll
            for (int j = 0; j < 4; ++j) {
                const int row = wm0 + j * 16 + (lane & 15);
                const int blk = (kk * 4 + (lane >> 4)) ^ (row & 7);
                bg[j] = *(const s16x8*)((const char*)Wt + row * 128 + blk * 16);
            }
#pragma unroll
            for (int i = 0; i < 4; ++i)
#pragma unroll
                for (int j = 0; j < 4; ++j)
                    acc[i][j] = __builtin_amdgcn_mfma_f32_16x16x32_bf16(
                        af[i], bg[j], acc[i][j], 0, 0, 0);
        }
    }

    // epilogue: token=(lane>>4)*4+reg, channel=lane&15
    const int chL = lane & 15, tq = (lane >> 4) * 4;
#pragma unroll
    for (int j = 0; j < 4; ++j) {
        const int ch = mb + wm0 + j * 16 + chL;
        const float bi = (kc == 0) ? bias[ch] : 0.f;
        if constexpr (OUTBF16) {
            short* Ob = (short*)Ov + nb * (size_t)M * S + (size_t)ch * S;
#pragma unroll
            for (int i = 0; i < 4; ++i) {
                const int t0 = sb + ws0 + i * 16 + tq;
                f32x4 a = acc[i][j];
                s16x4 o = (s16x4){f2bf(a.x + bi), f2bf(a.y + bi), f2bf(a.z + bi), f2bf(a.w + bi)};
                *(s16x4*)(Ob + t0) = o;
            }
        } else {
            float* Ob = (float*)Ov + ((KSPLIT > 1) ? (size_t)kc * NB * M * S : 0)
                        + nb * (size_t)M * S + (size_t)ch * S;
#pragma unroll
            for (int i = 0; i < 4; ++i) {
                const int t0 = sb + ws0 + i * 16 + tq;
                f32x4 a = acc[i][j];
                a.x += bi; a.y += bi; a.z += bi; a.w += bi;
                *(f32x4*)(Ob + t0) = a;
            }
        }
    }
}

// ---------------------------------------------------------------------------
// rp GEMM: out[ch][t] = rpW[ch][:] . aggT[t][:] + bias + residual, LN stats.
// BM=64 x BS=128, K=256. 4 waves (2m x 2s), wave tile 32m x 64s (32 AGPR).
// Double-buffered LDS + counted-vmcnt 2-phase pipeline (6 gload_lds/wave per
// stage; vmcnt(6) mid-loop, never 0).  XCD-bijective block swizzle: the 8
// m-tiles of one (s,n) panel land on one XCD -> shared aggT panel L2-hits.
// ---------------------------------------------------------------------------
__global__ __launch_bounds__(256, 3) void gemm_rp(
    const short* __restrict__ Wb, const float* __restrict__ bias,
    const short* __restrict__ Xv, float* __restrict__ O,
    const float* __restrict__ R, float* __restrict__ stats)
{
    __shared__ __align__(16) short Wt[2][64][64];    // 16 KB
    __shared__ __align__(16) short Xt[2][128][64];   // 32 KB

    const int tid  = threadIdx.x;
    const int lane = tid & 63;
    const int wave = tid >> 6;

    // decode: d%8 = XCD residue r; panels p ≡ r (mod 8); m-tiles contiguous
    const int d  = blockIdx.x;
    const int r  = d & 7;
    const int q  = d >> 3;
    const int mt = q & 7;
    const int p  = (q >> 3) * 8 + r;        // 0..391
    const int nb_ = p / 98;
    const int st  = p - nb_ * 98;
    const int mb = mt * 64;
    const int sb = st * 128;
    const size_t nb = (size_t)nb_;

    const int wm0 = (wave >> 1) * 32;       // 0 / 32
    const int ws0 = (wave & 1) * 64;        // 0 / 64

    f32x4 acc[2][4];
#pragma unroll
    for (int j = 0; j < 2; ++j)
#pragma unroll
        for (int i = 0; i < 4; ++i) acc[j][i] = (f32x4){0.f, 0.f, 0.f, 0.f};

    // staging: W 8 KB = 8 instrs (2/wave), X 16 KB = 16 instrs (4/wave)
    auto stage = [&](int buf, int k0) {
#pragma unroll
        for (int u = 0; u < 2; ++u) {
            const int uu = wave * 2 + u;                 // 0..7
            const int rr = uu * 8 + (lane >> 3);         // 0..63
            const int gblk = (lane & 7) ^ (rr & 7);
            const short* src = Wb + (size_t)(mb + rr) * 256 + k0 + gblk * 8;
            __builtin_amdgcn_global_load_lds(
                (const __attribute__((address_space(1))) unsigned*)src,
                (__attribute__((address_space(3))) unsigned*)((char*)Wt + buf * 8192 + uu * 1024),
                16, 0, 0);
        }
#pragma unroll
        for (int u = 0; u < 4; ++u) {
            const int uu = wave * 4 + u;                 // 0..15
            const int rr = uu * 8 + (lane >> 3);         // 0..127
            const int gblk = (lane & 7) ^ (rr & 7);
            const short* src = Xv + (nb * (size_t)S_TOK + sb + rr) * 256 + k0 + gblk * 8;
            __builtin_amdgcn_global_load_lds(
                (const __attribute__((address_space(1))) unsigned*)src,
                (__attribute__((address_space(3))) unsigned*)((char*)Xt + buf * 16384 + uu * 1024),
                16, 0, 0);
        }
    };

    auto compute = [&](int buf) {
#pragma unroll
        for (int kk = 0; kk < 2; ++kk) {
            s16x8 af[4], bg[2];
#pragma unroll
            for (int i = 0; i < 4; ++i) {
                const int row = ws0 + i * 16 + (lane & 15);
                const int blk = (kk * 4 + (lane >> 4)) ^ (row & 7);
                af[i] = *(const s16x8*)((const char*)Xt + buf * 16384 + row * 128 + blk * 16);
            }
#pragma unroll
            for (int j = 0; j < 2; ++j) {
                const int row = wm0 + j * 16 + (lane & 15);
                const int blk = (kk * 4 + (lane >> 4)) ^ (row & 7);
                bg[j] = *(const s16x8*)((const char*)Wt + buf * 8192 + row * 128 + blk * 16);
            }
#pragma unroll
            for (int j = 0; j < 2; ++j)
#pragma unroll
                for (int i = 0; i < 4; ++i)
                    acc[j][i] = __builtin_amdgcn_mfma_f32_16x16x32_bf16(
                        af[i], bg[j], acc[j][i], 0, 0, 0);
        }
    };

    // 2-phase pipeline over 4 k-steps (K=256, BK=64)
    stage(0, 0);
#pragma unroll
    for (int t = 0; t < 4; ++t) {
        if (t < 3) {
            stage((t + 1) & 1, (t + 1) * 64);
            asm volatile("s_waitcnt vmcnt(6)" ::: "memory");
        } else {
            asm volatile("s_waitcnt vmcnt(0)" ::: "memory");
        }
        __builtin_amdgcn_s_barrier();
        compute(t & 1);
        __builtin_amdgcn_s_barrier();
    }

    // epilogue: bias + residual + LN stats + fp32 store
    float lsum = 0.f, lss = 0.f;
    const int chL = lane & 15, tq = (lane >> 4) * 4;
#pragma unroll
    for (int j = 0; j < 2; ++j) {
        const int ch = mb + wm0 + j * 16 + chL;
        const float bi = bias[ch];
        float* orow = O + nb * (size_t)512 * S_TOK + (size_t)ch * S_TOK;
        const float* rrow = R + nb * (size_t)512 * S_TOK + (size_t)ch * S_TOK;
#pragma unroll
        for (int i = 0; i < 4; ++i) {
            const int t0 = sb + ws0 + i * 16 + tq;
            f32x4 a = acc[j][i];
            const float4 rv = *(const float4*)(rrow + t0);
            a.x += bi + rv.x; a.y += bi + rv.y; a.z += bi + rv.z; a.w += bi + rv.w;
            lsum += a.x + a.y + a.z + a.w;
            lss  += a.x * a.x + a.y * a.y + a.z * a.z + a.w * a.w;
            *(f32x4*)(orow + t0) = a;
        }
    }

#pragma unroll
    for (int o = 32; o; o >>= 1) {
        lsum += __shfl_down(lsum, o);
        lss  += __shfl_down(lss, o);
    }
    __shared__ float s1[4], s2[4];
    if (!lane) { s1[wave] = lsum; s2[wave] = lss; }
    __syncthreads();
    if (!tid) {
        atomicAdd(&stats[0], s1[0] + s1[1] + s1[2] + s1[3]);
        atomicAdd(&stats[1], s2[0] + s2[1] + s2[2] + s2[3]);
    }
}

// ---------------------------------------------------------------------------
// Depthwise 3x3x3 conv, pad 1, summing 2 pw1 K-split partials.
// Emits mid fp32 [c][t] (for KQ gemm) and midb bf16 [c][t] (for km).
// ---------------------------------------------------------------------------
__global__ __launch_bounds__(256) void dw_k(
    const float* __restrict__ p0, const float* __restrict__ w,
    const float* __restrict__ b, float* __restrict__ out,
    short* __restrict__ outb)
{
    const int idx = blockIdx.x;
    const int d = idx & 15;
    const int c = (idx >> 4) & 63;
    const int n = idx >> 10;

    float wr[27];
#pragma unroll
    for (int i = 0; i < 27; ++i) wr[i] = w[c * 27 + i];
    const float bb = b[c];

    const size_t slab = (size_t)(n * 64 + c) * 16 * 784;
    const float* b0 = p0 + slab;
    const float* b1 = p0 + 3211264 + slab;
    const size_t obase = ((size_t)(n * 64 + c) * 16 + d) * 784;
    float* ob = out + obase;
    short* obb = outb + obase;

    for (int p = threadIdx.x; p < 784; p += 256) {
        const int hh = p / 28, ww = p - hh * 28;
        float acc = bb;
#pragma unroll
        for (int kd = 0; kd < 3; ++kd) {
            const int dd = d + kd - 1;
            if ((unsigned)dd >= 16u) continue;
#pragma unroll
            for (int kh = 0; kh < 3; ++kh) {
                const int h2 = hh + kh - 1;
                if ((unsigned)h2 >= 28u) continue;
#pragma unroll
                for (int kw = 0; kw < 3; ++kw) {
                    const int w2 = ww + kw - 1;
                    if ((unsigned)w2 >= 28u) continue;
                    const size_t off = (size_t)dd * 784 + h2 * 28 + w2;
                    acc += (b0[off] + b1[off]) * wr[kd * 9 + kh * 3 + kw];
                }
            }
        }
        ob[p] = acc;
        obb[p] = f2bf(acc);
    }
}

// ---------------------------------------------------------------------------
// km (MFMA): per (n,h), KMp[chunk][nh][k][c] = sum_{t in chunk} exp(keys)*mid
// + partial sumexp.  keys bf16 [n][512][S] rows 0..255; midb bf16 [n][64][S].
// mx = 0 (exact: softmax shift-invariant; keys are O(1) so exp is safe).
// ---------------------------------------------------------------------------
__global__ __launch_bounds__(256) void km_k(
    const short* __restrict__ kqb, const short* __restrict__ midb,
    float* __restrict__ kmp, float* __restrict__ sep)
{
    const int chunk = blockIdx.x;
    const int wave = threadIdx.x >> 6;
    const int lane = threadIdx.x & 63;
    const int nh = blockIdx.y * 4 + wave;
    const int n = nh >> 3, h = nh & 7;

    const int row = lane & 15;
    const int t0base = chunk * 256 + (lane >> 4) * 8;

    const short* kbase = kqb + ((size_t)n * 512 + h * 32) * S_TOK;
    const short* mbase = midb + (size_t)n * 64 * S_TOK;

    f32x4 acc[2][4];
#pragma unroll
    for (int i = 0; i < 2; ++i)
#pragma unroll
        for (int j = 0; j < 4; ++j) acc[i][j] = (f32x4){0.f, 0.f, 0.f, 0.f};
    float se[2] = {0.f, 0.f};

#pragma unroll
    for (int st = 0; st < 8; ++st) {
        const int t0 = t0base + st * 32;
        s16x8 a[2];
#pragma unroll
        for (int i = 0; i < 2; ++i) {
            s16x8 kv = *(const s16x8*)(kbase + (size_t)(i * 16 + row) * S_TOK + t0);
            s16x8 e;
#pragma unroll
            for (int q = 0; q < 8; ++q) {
                const float f = __expf(bf2f(kv[q]));
                se[i] += f;
                e[q] = f2bf(f);
            }
            a[i] = e;
        }
#pragma unroll
        for (int j = 0; j < 4; ++j) {
            const s16x8 bfr = *(const s16x8*)(mbase + (size_t)(j * 16 + row) * S_TOK + t0);
#pragma unroll
            for (int i = 0; i < 2; ++i)
                acc[i][j] = __builtin_amdgcn_mfma_f32_16x16x32_bf16(a[i], bfr, acc[i][j], 0, 0, 0);
        }
    }

#pragma unroll
    for (int i = 0; i < 2; ++i) {
        se[i] += __shfl_xor(se[i], 16);
        se[i] += __shfl_xor(se[i], 32);
    }
    if (lane < 16) {
        sep[((size_t)chunk * 32 + nh) * 32 + row] = se[0];
        sep[((size_t)chunk * 32 + nh) * 32 + 16 + row] = se[1];
    }

    float* kp = kmp + ((size_t)chunk * 32 + nh) * 2048;
#pragma unroll
    for (int i = 0; i < 2; ++i)
#pragma unroll
        for (int j = 0; j < 4; ++j)
#pragma unroll
            for (int r = 0; r < 4; ++r) {
                const int k = i * 16 + (lane >> 4) * 4 + r;
                kp[k * 64 + j * 16 + row] = acc[i][j][r];
            }
}

// ---------------------------------------------------------------------------
// Context: ctx[nh][k][v] = v_b + (sum_p KMp / sum_p sep) @ v_w^T
// ---------------------------------------------------------------------------
__global__ __launch_bounds__(1024) void ctx_k(
    const float* __restrict__ kmp, const float* __restrict__ sep,
    const float* __restrict__ vw, const float* __restrict__ vb,
    float* __restrict__ ctx)
{
    __shared__ float KM[32][64];
    __shared__ float ses[32];
    const int nh = blockIdx.x;
    const int tid = threadIdx.x;

    if (tid < 32) {
        float s = 0.f;
        for (int p = 0; p < 49; ++p) s += sep[((size_t)p * 32 + nh) * 32 + tid];
        ses[tid] = s;
    }
    __syncthreads();

    for (int e = tid; e < 2048; e += 1024) {
        const int k = e >> 6, c = e & 63;
        float s = 0.f;
        for (int p = 0; p < 49; ++p)
            s += kmp[((size_t)p * 32 + nh) * 2048 + e];
        KM[k][c] = s / ses[k];
    }
    __syncthreads();

    const int k = tid >> 5, v = tid & 31;
    const int hv = (nh & 7) * 32 + v;
    float acc = vb[hv];
#pragma unroll
    for (int c = 0; c < 64; ++c) acc += KM[k][c] * vw[hv * 64 + c];
    ctx[((size_t)nh * 32 + k) * 32 + v] = acc;
}

// ---------------------------------------------------------------------------
// Query softmax + attended; queries bf16 rows 256..511 of kqb.
// Writes aggT bf16 [n][t][256] token-major.
// ---------------------------------------------------------------------------
__global__ __launch_bounds__(256) void attn_k(
    const short* __restrict__ kqb, const float* __restrict__ ctx,
    short* __restrict__ aggT)
{
    __shared__ float Cl[32][32];
    const int n = blockIdx.z, h = blockIdx.y;
    const int t = blockIdx.x * 256 + threadIdx.x;
    const int nh = n * 8 + h;

    for (int e = threadIdx.x; e < 1024; e += 256)
        Cl[e >> 5][e & 31] = ctx[(size_t)nh * 1024 + e];
    __syncthreads();

    float qs[32];
    const short* qb = kqb + ((size_t)n * 512 + 256 + h * 32) * S_TOK + t;
    float mx = -INFINITY;
#pragma unroll
    for (int k = 0; k < 32; ++k) {
        qs[k] = bf2f(qb[(size_t)k * S_TOK]);
        mx = fmaxf(mx, qs[k]);
    }
    float s = 0.f;
#pragma unroll
    for (int k = 0; k < 32; ++k) {
        qs[k] = __expf(qs[k] - mx);
        s += qs[k];
    }
    const float inv = 1.0f / s;

    short* ab = aggT + ((size_t)n * S_TOK + t) * 256 + h * 32;
#pragma unroll
    for (int u = 0; u < 4; ++u) {
        s16x8 o;
#pragma unroll
        for (int e = 0; e < 8; ++e) {
            const int v = u * 8 + e;
            float a = 0.f;
#pragma unroll
            for (int k = 0; k < 32; ++k) a += Cl[k][v] * qs[k];
            o[e] = f2bf(a * inv);
        }
        *(s16x8*)(ab + u * 8) = o;
    }
}

// ---------------------------------------------------------------------------
// Final whole-tensor layernorm, in-place.
// ---------------------------------------------------------------------------
__global__ __launch_bounds__(256) void ln_k(
    float* __restrict__ O, const float* __restrict__ stats, size_t n4)
{
    const float NT = (float)N_TOTAL;
    const float mu = stats[0] / NT;
    const float var = stats[1] / NT - mu * mu;
    const float inv = rsqrtf(var + EPS);
    float4* p = (float4*)O;
    for (size_t i = (size_t)blockIdx.x * blockDim.x + threadIdx.x; i < n4;
         i += (size_t)gridDim.x * blockDim.x) {
        float4 v = p[i];
        v.x = (v.x - mu) * inv;
        v.y = (v.y - mu) * inv;
        v.z = (v.z - mu) * inv;
        v.w = (v.w - mu) * inv;
        p[i] = v;
    }
}

// ---------------------------------------------------------------------------
extern "C" void kernel_launch(void* const* d_in, const int* in_sizes, int n_in,
                              void* d_out, int out_size, void* d_ws, size_t ws_size,
                              hipStream_t stream)
{
    const float* x     = (const float*)d_in[0];
    const float* pw1_w = (const float*)d_in[1];
    const float* pw1_b = (const float*)d_in[2];
    const float* dw_w  = (const float*)d_in[3];
    const float* dw_b  = (const float*)d_in[4];
    const float* k_w   = (const float*)d_in[5];
    const float* k_b   = (const float*)d_in[6];
    const float* q_w   = (const float*)d_in[7];
    const float* q_b   = (const float*)d_in[8];
    const float* v_w   = (const float*)d_in[9];
    const float* v_b   = (const float*)d_in[10];
    const float* rp_w  = (const float*)d_in[11];
    const float* rp_b  = (const float*)d_in[12];
    float* out = (float*)d_out;

    // workspace (float units)
    float* ws      = (float*)d_ws;
    float* lnstats = ws;                        // 16
    float* biaskq  = ws + 16;                   // 512
    float* sep     = ws + 528;                  // 50176
    float* ctx     = ws + 50704;                // 32768
    float* kmp     = ws + 83472;                // 3,211,264
    float* mid0p   = ws + 3294736;              // 2 x 3,211,264 (pw1 K-split partials)
    float* mid     = ws + 9717264;              // 3,211,264 fp32 [c][t]
    short* midb    = (short*)(ws + 12928528);   // 3,211,264 bf16 [c][t]
    short* kqb     = (short*)(ws + 14534160);   // 4*512*12544 bf16 (keys+queries)
    short* aggT    = (short*)(ws + 27379216);   // 4*12544*256 bf16 token-major
    short* wb      = (short*)(ws + 33801744);   // 196,608 bf16 weights

    hipMemsetAsync(lnstats, 0, 2 * sizeof(float), stream);

    const dim3 b256(256);

    // 0) weights -> bf16 (+ stacked kq bias)
    prep_k<<<dim3(192), b256, 0, stream>>>(pw1_w, k_w, q_w, rp_w, k_b, q_b, wb, biaskq);
    // 1) pointwise 512->64, K-split x2 into partial buffers
    gemm_mfma<128, 1, 2, false, 2><<<dim3(2, 98, NB), dim3(128), 0, stream>>>(
        wb, pw1_b, x, mid0p, 64, 512, S_TOK);
    // 2) depthwise 3x3x3 (sums partials; emits fp32 + bf16 mid)
    dw_k<<<dim3(4096), b256, 0, stream>>>(mid0p, dw_w, dw_b, mid, midb);
    // 3) fused K+Q 64->512, bf16 out
    gemm_mfma<256, 2, 2, true, 1><<<dim3(4, 98, NB), b256, 0, stream>>>(
        wb + 32768, biaskq, mid, kqb, 512, 64, S_TOK);
    // 4) KM partials + sumexp partials (MFMA, mx=0)
    km_k<<<dim3(49, 8), b256, 0, stream>>>(kqb, midb, kmp, sep);
    // 5) context
    ctx_k<<<dim3(32), dim3(1024), 0, stream>>>(kmp, sep, v_w, v_b, ctx);
    // 6) query softmax + attended -> aggT
    attn_k<<<dim3(49, 8, NB), b256, 0, stream>>>(kqb, ctx, aggT);
    // 7) reprojection: dbuf pipeline + XCD swizzle + residual + LN stats
    gemm_rp<<<dim3(3136), b256, 0, stream>>>(wb + 65536, rp_b, aggT, out, x, lnstats);
    // 8) layernorm finalize
    ln_k<<<dim3(2048), b256, 0, stream>>>(out, lnstats, N_TOTAL / 4);
}